// Round 8
// baseline (299.091 us; speedup 1.0000x reference)
//
#include <hip/hip_runtime.h>
#include <cstdint>
#include <cstddef>

// ---------- types / helpers ----------
typedef __bf16 bf16x8 __attribute__((ext_vector_type(8)));
typedef float  f32x4  __attribute__((ext_vector_type(4)));
typedef unsigned short us;

#define DEV static __device__ __forceinline__

DEV us f2bf(float f) {
    unsigned int u = __builtin_bit_cast(unsigned int, f);
    u += 0x7FFFu + ((u >> 16) & 1u);   // RNE
    return (us)(u >> 16);
}
DEV unsigned int pack2bf(float a, float b) {   // [lo=a, hi=b], round-half-up (cheap)
    unsigned int ua = __builtin_bit_cast(unsigned int, a) + 0x8000u;
    unsigned int ub = __builtin_bit_cast(unsigned int, b) + 0x8000u;
    return (ua >> 16) | (ub & 0xFFFF0000u);    // -> v_perm_b32
}

DEV void gll16(const void* g, void* l) {   // 16B global->LDS direct (wave: +lane*16)
    __builtin_amdgcn_global_load_lds(
        (const __attribute__((address_space(1))) unsigned int*)g,
        (__attribute__((address_space(3))) unsigned int*)l, 16, 0, 0);
}

DEV bf16x8 ld_frag(const us* p) {
    return __builtin_bit_cast(bf16x8, *reinterpret_cast<const uint4*>(p));
}

// ---------- problem constants ----------
#define BB 4
#define TT 2048
#define CC 768
#define NH 12
#define DH 64
#define MM (BB*TT)          // 8192
#define QSCALE 0.1803368801111144f   // 0.125 * log2(e): softmax via exp2

// ---------- cast f32 -> bf16 ----------
__global__ __launch_bounds__(256)
void cast_k(const float* __restrict__ x, us* __restrict__ xb, int n4)
{
    int i = blockIdx.x * 256 + threadIdx.x;
    int stride = gridDim.x * 256;
    for (; i < n4; i += stride) {
        float4 f = reinterpret_cast<const float4*>(x)[i];
        ushort4 o;
        o.x = f2bf(f.x); o.y = f2bf(f.y); o.z = f2bf(f.z); o.w = f2bf(f.w);
        reinterpret_cast<ushort4*>(xb)[i] = o;
    }
}

// ---------- transpose f32 -> bf16: dst[Cc][R] = bf16(src[R][Cc]) ----------
__global__ __launch_bounds__(256)
void transpose_k(const float* __restrict__ src,
                 us* __restrict__ dst, int R, int Cc)
{
    __shared__ float tile[32][33];
    int c0 = blockIdx.x * 32, r0 = blockIdx.y * 32;
    int tx = threadIdx.x, ty = threadIdx.y;
#pragma unroll
    for (int i = 0; i < 4; ++i)
        tile[ty + i*8][tx] = src[(size_t)(r0 + ty + i*8) * Cc + c0 + tx];
    __syncthreads();
#pragma unroll
    for (int i = 0; i < 4; ++i)
        dst[(size_t)(c0 + ty + i*8) * R + r0 + tx] = f2bf(tile[tx][ty + i*8]);
}

// ---------- GEMM: C[M,N] = A[M,K](bf16) * Bt[N,K]^T + bias[N] ----------
// MODE 0: store f32 to Cout
// MODE 1: scatter qkv -> Qo(scaled)[B,H,T,D] / Ko[B,H,T,D] / Vo^T[B,H,D,T] bf16
#define BM 128
#define BN 128
#define BK 64

template<int MODE>
__global__ __launch_bounds__(256)
void gemm_bt(const us* __restrict__ A,
             const us* __restrict__ Bt,
             const float* __restrict__ bias,
             float* __restrict__ Cout,
             us* __restrict__ Qo, us* __restrict__ Ko, us* __restrict__ Vo,
             int M, int N, int K)
{
    __shared__ __align__(16) us As[BM * BK];
    __shared__ __align__(16) us Bs[BN * BK];

    const int tid  = threadIdx.x;
    const int wave = tid >> 6, lane = tid & 63;
    const int quad = lane >> 4, l16 = lane & 15;
    const int waveM = (wave >> 1) * 64, waveN = (wave & 1) * 64;
    const int m0 = blockIdx.y * BM, n0 = blockIdx.x * BN;

    const f32x4 zero4 = {0.f, 0.f, 0.f, 0.f};
    f32x4 acc[4][4];
#pragma unroll
    for (int i = 0; i < 4; ++i)
#pragma unroll
        for (int j = 0; j < 4; ++j) acc[i][j] = zero4;

    const int lrow = lane >> 3, lch = (lane & 7) * 8;   // 8 rows x 64 cols per wave-inst
    const int nk = K / BK;
    for (int kt = 0; kt < nk; ++kt) {
#pragma unroll
        for (int c = 0; c < 4; ++c) {
            int rb = (wave * 4 + c) * 8;
            int row = rb + lrow;
            gll16(A  + (size_t)(m0 + row) * K + kt * BK + lch, &As[rb * BK]);
            gll16(Bt + (size_t)(n0 + row) * K + kt * BK + lch, &Bs[rb * BK]);
        }
        __syncthreads();

#pragma unroll
        for (int ks = 0; ks < 2; ++ks) {
            bf16x8 af[4], bfv[4];
#pragma unroll
            for (int mi = 0; mi < 4; ++mi)
                af[mi] = *reinterpret_cast<const bf16x8*>(&As[(waveM + mi * 16 + l16) * BK + ks * 32 + quad * 8]);
#pragma unroll
            for (int ni = 0; ni < 4; ++ni)
                bfv[ni] = *reinterpret_cast<const bf16x8*>(&Bs[(waveN + ni * 16 + l16) * BK + ks * 32 + quad * 8]);
#pragma unroll
            for (int mi = 0; mi < 4; ++mi)
#pragma unroll
                for (int ni = 0; ni < 4; ++ni)
                    acc[mi][ni] = __builtin_amdgcn_mfma_f32_16x16x32_bf16(af[mi], bfv[ni], acc[mi][ni], 0, 0, 0);
        }
        __syncthreads();
    }

    // epilogue: C/D layout col = l16, row = quad*4 + reg
#pragma unroll
    for (int mi = 0; mi < 4; ++mi) {
#pragma unroll
        for (int ni = 0; ni < 4; ++ni) {
            int n = n0 + waveN + ni * 16 + l16;
            float bv = bias[n];
            int mg = m0 + waveM + mi * 16 + quad * 4;   // first of 4 consecutive m
            if (MODE == 0) {
#pragma unroll
                for (int reg = 0; reg < 4; ++reg)
                    Cout[(size_t)(mg + reg) * N + n] = acc[mi][ni][reg] + bv;
            } else {
                int which = n / CC, c2 = n % CC;
                int h = c2 >> 6, d = c2 & 63;
                int b = mg >> 11, t0 = mg & 2047;
                if (which == 2) {
                    // V^T [B,H,D,T]: 4 consecutive t -> one 8B store
                    ushort4 pk;
                    pk.x = f2bf(acc[mi][ni][0] + bv);
                    pk.y = f2bf(acc[mi][ni][1] + bv);
                    pk.z = f2bf(acc[mi][ni][2] + bv);
                    pk.w = f2bf(acc[mi][ni][3] + bv);
                    *reinterpret_cast<ushort4*>(Vo + ((size_t)(b * NH + h) * DH + d) * TT + t0) = pk;
                } else {
#pragma unroll
                    for (int reg = 0; reg < 4; ++reg) {
                        size_t off = ((size_t)(b * NH + h) * TT + t0 + reg) * DH + d;
                        float v = acc[mi][ni][reg] + bv;
                        if (which == 0) Qo[off] = f2bf(v * QSCALE);
                        else            Ko[off] = f2bf(v);
                    }
                }
            }
        }
    }
}

// ---------- flash attention (causal), paired qtiles, XCD-local heads ----------
// 1D grid 768. Decode (assuming round-robin XCD = id%8): all 16 q-blocks of a
// head land on one XCD -> per-XCD K/V working set = 6 heads x 512 KB = 3 MB < 4 MB L2.
// Block handles qtiles {px, 31-px}: exactly 33 key-tile iters (perfect balance).
#define KST 72
#define PST 72

__global__ __launch_bounds__(256)
void attn_k(const us* __restrict__ Qg,
            const us* __restrict__ Kg,
            const us* __restrict__ Vt,   // V^T [B,H,D,T]
            us* __restrict__ Og)
{
    __shared__ __align__(16) us Ks[64 * KST];      // [key][d]
    __shared__ __align__(16) us Vs[64 * KST];      // [d][key]
    __shared__ __align__(16) us Ps[4][16 * PST];   // per-wave [m][key]

    const int tid  = threadIdx.x;
    const int wave = tid >> 6, lane = tid & 63;
    const int quad = lane >> 4, l16 = lane & 15;

    // XCD-locality decode
    const int id  = blockIdx.x;
    const int xcd = id & 7, s = id >> 3;
    const int bh  = xcd + 8 * (s >> 4);            // head index 0..47, fixed XCD
    const int px  = s & 15;                        // pair index 0..15

    const size_t base  = (size_t)bh * TT * DH;     // Q/K
    const size_t baseV = (size_t)bh * DH * TT;     // V^T
    const int b = bh / NH, h = bh % NH;
    us* myP = Ps[wave];

    const int r0 = tid >> 3, c0 = (tid & 7) * 8;           // staging row/col (i=0)
    const int r1 = (tid + 256) >> 3, c1 = ((tid + 256) & 7) * 8;

    // prefetch key-tile 0
    uint4 kpre[2], vpre[2];
    kpre[0] = *reinterpret_cast<const uint4*>(Kg + base  + (size_t)r0 * DH + c0);
    kpre[1] = *reinterpret_cast<const uint4*>(Kg + base  + (size_t)r1 * DH + c1);
    vpre[0] = *reinterpret_cast<const uint4*>(Vt + baseV + (size_t)r0 * TT + c0);
    vpre[1] = *reinterpret_cast<const uint4*>(Vt + baseV + (size_t)r1 * TT + c1);

    const f32x4 zero4 = {0.f, 0.f, 0.f, 0.f};

#pragma unroll 1
    for (int seg = 0; seg < 2; ++seg) {
        const int qt  = seg ? 31 - px : px;
        const int nkt = qt + 1;
        const int m = qt * 64 + wave * 16 + l16;   // this lane's query row

        bf16x8 qf0 = ld_frag(Qg + base + (size_t)m * DH + quad * 8);
        bf16x8 qf1 = ld_frag(Qg + base + (size_t)m * DH + 32 + quad * 8);

        f32x4 o[4];
#pragma unroll
        for (int i = 0; i < 4; ++i) o[i] = zero4;
        float mr = -INFINITY, lr = 0.f;

#pragma unroll 1
        for (int j = 0; j < nkt; ++j) {
            // commit prefetched tile to LDS
            *reinterpret_cast<uint4*>(&Ks[r0 * KST + c0]) = kpre[0];
            *reinterpret_cast<uint4*>(&Ks[r1 * KST + c1]) = kpre[1];
            *reinterpret_cast<uint4*>(&Vs[r0 * KST + c0]) = vpre[0];
            *reinterpret_cast<uint4*>(&Vs[r1 * KST + c1]) = vpre[1];

            __syncthreads();   // tile visible to all waves

            // prefetch next tile (issues now, lands during compute phase; L2-hit)
            int nj = j + 1, valid = 1;
            if (nj == nkt) { nj = (seg == 0) ? 0 : -1; valid = (seg == 0); }
            if (valid) {
                const us* kb = Kg + base  + (size_t)nj * 64 * DH;
                const us* vb = Vt + baseV + nj * 64;
                kpre[0] = *reinterpret_cast<const uint4*>(kb + (size_t)r0 * DH + c0);
                kpre[1] = *reinterpret_cast<const uint4*>(kb + (size_t)r1 * DH + c1);
                vpre[0] = *reinterpret_cast<const uint4*>(vb + (size_t)r0 * TT + c0);
                vpre[1] = *reinterpret_cast<const uint4*>(vb + (size_t)r1 * TT + c1);
            }

            // S^T = K Q^T : rows = key, col = m (l16)
            f32x4 s4[4];
#pragma unroll
            for (int sub = 0; sub < 4; ++sub) {
                bf16x8 k0 = *reinterpret_cast<const bf16x8*>(&Ks[(sub * 16 + l16) * KST + quad * 8]);
                bf16x8 k1 = *reinterpret_cast<const bf16x8*>(&Ks[(sub * 16 + l16) * KST + 32 + quad * 8]);
                f32x4 t = __builtin_amdgcn_mfma_f32_16x16x32_bf16(k0, qf0, zero4, 0, 0, 0);
                s4[sub]  = __builtin_amdgcn_mfma_f32_16x16x32_bf16(k1, qf1, t, 0, 0, 0);
            }

            // diagonal mask on last tile of segment
            if (j == nkt - 1) {
#pragma unroll
                for (int sub = 0; sub < 4; ++sub)
#pragma unroll
                    for (int reg = 0; reg < 4; ++reg)
                        if (j * 64 + sub * 16 + quad * 4 + reg > m) s4[sub][reg] = -INFINITY;
            }

            // per-lane online softmax (16 vals + 2 shuffles)
            float mx = -INFINITY;
#pragma unroll
            for (int sub = 0; sub < 4; ++sub)
#pragma unroll
                for (int reg = 0; reg < 4; ++reg) mx = fmaxf(mx, s4[sub][reg]);
            mx = fmaxf(mx, __shfl_xor(mx, 16));
            mx = fmaxf(mx, __shfl_xor(mx, 32));
            float mnew = fmaxf(mr, mx);
            float alpha = exp2f(mr - mnew);
            float rs = 0.f;
#pragma unroll
            for (int sub = 0; sub < 4; ++sub) {
                float p0 = exp2f(s4[sub][0] - mnew), p1 = exp2f(s4[sub][1] - mnew);
                float p2 = exp2f(s4[sub][2] - mnew), p3 = exp2f(s4[sub][3] - mnew);
                rs += (p0 + p1) + (p2 + p3);
                uint2 pk;
                pk.x = pack2bf(p0, p1);
                pk.y = pack2bf(p2, p3);
                *reinterpret_cast<uint2*>(&myP[l16 * PST + sub * 16 + quad * 4]) = pk;
            }
            rs += __shfl_xor(rs, 16);
            rs += __shfl_xor(rs, 32);
            lr = lr * alpha + rs;
            mr = mnew;
#pragma unroll
            for (int d = 0; d < 4; ++d) o[d] *= alpha;

            // O^T += V^T P (per-wave; P round-trip needs no barrier)
#pragma unroll
            for (int kc = 0; kc < 2; ++kc) {
                bf16x8 pf = *reinterpret_cast<const bf16x8*>(&myP[l16 * PST + kc * 32 + quad * 8]);
#pragma unroll
                for (int d = 0; d < 4; ++d) {
                    bf16x8 vf = *reinterpret_cast<const bf16x8*>(&Vs[(d * 16 + l16) * KST + kc * 32 + quad * 8]);
                    o[d] = __builtin_amdgcn_mfma_f32_16x16x32_bf16(vf, pf, o[d], 0, 0, 0);
                }
            }

            __syncthreads();   // all reads done before next commit overwrites Ks/Vs
        }

        // epilogue for this segment: O^T[d][m] -> att[b, t=m, h*64+d]
        const float inv = 1.f / lr;
        us* orow = Og + ((size_t)(b * TT + m)) * CC + h * DH;
#pragma unroll
        for (int d = 0; d < 4; ++d) {
            uint2 pk;
            pk.x = pack2bf(o[d][0] * inv, o[d][1] * inv);
            pk.y = pack2bf(o[d][2] * inv, o[d][3] * inv);
            *reinterpret_cast<uint2*>(orow + d * 16 + quad * 4) = pk;
        }
    }
}

// ---------- launch ----------
extern "C" void kernel_launch(void* const* d_in, const int* in_sizes, int n_in,
                              void* d_out, int out_size, void* d_ws, size_t ws_size,
                              hipStream_t stream)
{
    const float* x      = (const float*)d_in[0];
    const float* w_attn = (const float*)d_in[1];
    const float* b_attn = (const float*)d_in[2];
    const float* w_proj = (const float*)d_in[3];
    const float* b_proj = (const float*)d_in[4];
    float* out = (float*)d_out;

    char* ws = (char*)d_ws;
    size_t off = 0;
    auto alloc = [&](size_t bytes) {
        void* p = ws + off;
        off += (bytes + 255) & ~(size_t)255;
        return p;
    };
    us* wtA = (us*)alloc((size_t)(3 * CC) * CC * 2);  // [2304][768] bf16
    us* wtP = (us*)alloc((size_t)CC * CC * 2);        // [768][768]  bf16
    us* xb  = (us*)alloc((size_t)MM * CC * 2);        // x as bf16
    us* Qb  = (us*)alloc((size_t)MM * CC * 2);        // [B,H,T,D]
    us* Kb  = (us*)alloc((size_t)MM * CC * 2);        // [B,H,T,D]
    us* Vtb = (us*)alloc((size_t)MM * CC * 2);        // V^T [B,H,D,T]
    us* att = (us*)alloc((size_t)MM * CC * 2);        // [B,T,C]

    cast_k<<<1024, 256, 0, stream>>>(x, xb, MM * CC / 4);
    transpose_k<<<dim3((3 * CC) / 32, CC / 32), dim3(32, 8), 0, stream>>>(w_attn, wtA, CC, 3 * CC);
    transpose_k<<<dim3(CC / 32, CC / 32), dim3(32, 8), 0, stream>>>(w_proj, wtP, CC, CC);

    gemm_bt<1><<<dim3((3 * CC) / BN, MM / BM), 256, 0, stream>>>(
        xb, wtA, b_attn, nullptr, Qb, Kb, Vtb, MM, 3 * CC, CC);

    attn_k<<<dim3(16 * BB * NH), 256, 0, stream>>>(Qb, Kb, Vtb, att);

    gemm_bt<0><<<dim3(CC / BN, MM / BM), 256, 0, stream>>>(
        att, wtP, b_proj, out, nullptr, nullptr, nullptr, MM, CC, CC);

    (void)in_sizes; (void)n_in; (void)out_size; (void)ws_size;
}

// Round 9
// 265.918 us; speedup vs baseline: 1.1247x; 1.1247x over previous
//
#include <hip/hip_runtime.h>
#include <cstdint>
#include <cstddef>

// ---------- types / helpers ----------
typedef __bf16 bf16x8 __attribute__((ext_vector_type(8)));
typedef float  f32x4  __attribute__((ext_vector_type(4)));
typedef unsigned short us;

#define DEV static __device__ __forceinline__

DEV us f2bf(float f) {
    unsigned int u = __builtin_bit_cast(unsigned int, f);
    u += 0x7FFFu + ((u >> 16) & 1u);   // RNE
    return (us)(u >> 16);
}
DEV unsigned int pack2bf(float a, float b) {   // [lo=a, hi=b], round-half-up (cheap)
    unsigned int ua = __builtin_bit_cast(unsigned int, a) + 0x8000u;
    unsigned int ub = __builtin_bit_cast(unsigned int, b) + 0x8000u;
    return (ua >> 16) | (ub & 0xFFFF0000u);    // -> v_perm_b32
}

DEV void gll16(const void* g, void* l) {   // 16B global->LDS direct (wave: +lane*16)
    __builtin_amdgcn_global_load_lds(
        (const __attribute__((address_space(1))) unsigned int*)g,
        (__attribute__((address_space(3))) unsigned int*)l, 16, 0, 0);
}

DEV bf16x8 ld_frag(const us* p) {
    return __builtin_bit_cast(bf16x8, *reinterpret_cast<const uint4*>(p));
}

// ---------- problem constants ----------
#define BB 4
#define TT 2048
#define CC 768
#define NH 12
#define DH 64
#define MM (BB*TT)          // 8192
#define QSCALE 0.1803368801111144f   // 0.125 * log2(e): softmax via exp2

// ---------- cast f32 -> bf16 ----------
__global__ __launch_bounds__(256)
void cast_k(const float* __restrict__ x, us* __restrict__ xb, int n4)
{
    int i = blockIdx.x * 256 + threadIdx.x;
    int stride = gridDim.x * 256;
    for (; i < n4; i += stride) {
        float4 f = reinterpret_cast<const float4*>(x)[i];
        ushort4 o;
        o.x = f2bf(f.x); o.y = f2bf(f.y); o.z = f2bf(f.z); o.w = f2bf(f.w);
        reinterpret_cast<ushort4*>(xb)[i] = o;
    }
}

// ---------- transpose f32 -> bf16: dst[Cc][R] = bf16(src[R][Cc]) ----------
__global__ __launch_bounds__(256)
void transpose_k(const float* __restrict__ src,
                 us* __restrict__ dst, int R, int Cc)
{
    __shared__ float tile[32][33];
    int c0 = blockIdx.x * 32, r0 = blockIdx.y * 32;
    int tx = threadIdx.x, ty = threadIdx.y;
#pragma unroll
    for (int i = 0; i < 4; ++i)
        tile[ty + i*8][tx] = src[(size_t)(r0 + ty + i*8) * Cc + c0 + tx];
    __syncthreads();
#pragma unroll
    for (int i = 0; i < 4; ++i)
        dst[(size_t)(c0 + ty + i*8) * R + r0 + tx] = f2bf(tile[tx][ty + i*8]);
}

// ---------- GEMM: C[M,N] = A[M,K](bf16) * Bt[N,K]^T + bias[N] ----------
// MODE 0: store f32 to Cout
// MODE 1: scatter qkv -> Qo(scaled)[B,H,T,D] / Ko[B,H,T,D] / Vo^T[B,H,D,T] bf16
#define BM 128
#define BN 128
#define BK 32

template<int MODE>
__global__ __launch_bounds__(256)
void gemm_bt(const us* __restrict__ A,
             const us* __restrict__ Bt,
             const float* __restrict__ bias,
             float* __restrict__ Cout,
             us* __restrict__ Qo, us* __restrict__ Ko, us* __restrict__ Vo,
             int M, int N, int K)
{
    __shared__ __align__(16) us As[BM * BK];
    __shared__ __align__(16) us Bs[BN * BK];

    const int tid  = threadIdx.x;
    const int wave = tid >> 6, lane = tid & 63;
    const int quad = lane >> 4, l16 = lane & 15;
    const int waveM = (wave >> 1) * 64, waveN = (wave & 1) * 64;
    const int m0 = blockIdx.y * BM, n0 = blockIdx.x * BN;

    const f32x4 zero4 = {0.f, 0.f, 0.f, 0.f};
    f32x4 acc[4][4];
#pragma unroll
    for (int i = 0; i < 4; ++i)
#pragma unroll
        for (int j = 0; j < 4; ++j) acc[i][j] = zero4;

    const int lrow = lane >> 2, lch = (lane & 3) * 8;
    const int nk = K / BK;
    for (int kt = 0; kt < nk; ++kt) {
#pragma unroll
        for (int c = 0; c < 2; ++c) {
            int rb = (wave * 2 + c) * 16;
            int row = rb + lrow;
            gll16(A  + (size_t)(m0 + row) * K + kt * BK + lch, &As[rb * BK]);
            gll16(Bt + (size_t)(n0 + row) * K + kt * BK + lch, &Bs[rb * BK]);
        }
        __syncthreads();

        bf16x8 af[4], bfv[4];
#pragma unroll
        for (int mi = 0; mi < 4; ++mi)
            af[mi] = *reinterpret_cast<const bf16x8*>(&As[(waveM + mi * 16 + l16) * BK + quad * 8]);
#pragma unroll
        for (int ni = 0; ni < 4; ++ni)
            bfv[ni] = *reinterpret_cast<const bf16x8*>(&Bs[(waveN + ni * 16 + l16) * BK + quad * 8]);
#pragma unroll
        for (int mi = 0; mi < 4; ++mi)
#pragma unroll
            for (int ni = 0; ni < 4; ++ni)
                acc[mi][ni] = __builtin_amdgcn_mfma_f32_16x16x32_bf16(af[mi], bfv[ni], acc[mi][ni], 0, 0, 0);
        __syncthreads();
    }

    // epilogue: C/D layout col = l16, row = quad*4 + reg
#pragma unroll
    for (int mi = 0; mi < 4; ++mi) {
#pragma unroll
        for (int ni = 0; ni < 4; ++ni) {
            int n = n0 + waveN + ni * 16 + l16;
            float bv = bias[n];
            int mg = m0 + waveM + mi * 16 + quad * 4;   // first of 4 consecutive m
            if (MODE == 0) {
#pragma unroll
                for (int reg = 0; reg < 4; ++reg)
                    Cout[(size_t)(mg + reg) * N + n] = acc[mi][ni][reg] + bv;
            } else {
                int which = n / CC, c2 = n % CC;
                int h = c2 >> 6, d = c2 & 63;
                int b = mg >> 11, t0 = mg & 2047;
                if (which == 2) {
                    // V^T [B,H,D,T]: 4 consecutive t -> one 8B store
                    ushort4 pk;
                    pk.x = f2bf(acc[mi][ni][0] + bv);
                    pk.y = f2bf(acc[mi][ni][1] + bv);
                    pk.z = f2bf(acc[mi][ni][2] + bv);
                    pk.w = f2bf(acc[mi][ni][3] + bv);
                    *reinterpret_cast<ushort4*>(Vo + ((size_t)(b * NH + h) * DH + d) * TT + t0) = pk;
                } else {
#pragma unroll
                    for (int reg = 0; reg < 4; ++reg) {
                        size_t off = ((size_t)(b * NH + h) * TT + t0 + reg) * DH + d;
                        float v = acc[mi][ni][reg] + bv;
                        if (which == 0) Qo[off] = f2bf(v * QSCALE);
                        else            Ko[off] = f2bf(v);
                    }
                }
            }
        }
    }
}

// ---------- flash attention (causal): barrier-free, wave = 32 q-rows, L2-direct K/V ----------
// Grid 768 x 128 threads (2 waves). XCD decode keeps each head's K/V on one XCD's L2.
// Wave w of block (q) handles pair {pw, 63-pw}, pw = 2q+w: exactly 33 key-tile iters.
// K/V MFMA fragments loaded straight from global (L2-hit); P per-wave LDS round-trip.
// NO __syncthreads in this kernel.
#define PST 72

__global__ __launch_bounds__(128)
void attn_k(const us* __restrict__ Qg,
            const us* __restrict__ Kg,
            const us* __restrict__ Vt,   // V^T [B,H,D,T]
            us* __restrict__ Og)
{
    __shared__ __align__(16) us Ps[2][32 * PST];   // per-wave P[g*16+m][key]

    const int tid  = threadIdx.x;
    const int wave = tid >> 6, lane = tid & 63;
    const int quad = lane >> 4, l16 = lane & 15;

    // XCD-locality decode: xcd = id%8 (round-robin dispatch heuristic)
    const int id  = blockIdx.x;
    const int xcd = id & 7, s = id >> 3;           // s in 0..95
    const int bh  = xcd + 8 * (s >> 4);            // head 0..47, fixed XCD
    const int q   = s & 15;                        // 0..15
    const int pw  = 2 * q + wave;                  // wave's pair index 0..31

    const size_t base  = (size_t)bh * TT * DH;     // Q/K
    const size_t baseV = (size_t)bh * DH * TT;     // V^T
    const int b = bh / NH, h = bh % NH;
    us* myP = Ps[wave];

    const f32x4 zero4 = {0.f, 0.f, 0.f, 0.f};

#pragma unroll 1
    for (int seg = 0; seg < 2; ++seg) {
        const int g   = seg ? 63 - pw : pw;        // 32-row group index 0..63
        const int nkt = (g >> 1) + 1;              // key tiles of 64
        const int mA  = g * 32 + l16;              // group A query row
        const int mB  = mA + 16;                   // group B query row

        bf16x8 qfA0 = ld_frag(Qg + base + (size_t)mA * DH + quad * 8);
        bf16x8 qfA1 = ld_frag(Qg + base + (size_t)mA * DH + 32 + quad * 8);
        bf16x8 qfB0 = ld_frag(Qg + base + (size_t)mB * DH + quad * 8);
        bf16x8 qfB1 = ld_frag(Qg + base + (size_t)mB * DH + 32 + quad * 8);

        f32x4 oA[4], oB[4];
#pragma unroll
        for (int i = 0; i < 4; ++i) { oA[i] = zero4; oB[i] = zero4; }
        float mrA = -INFINITY, lrA = 0.f, mrB = -INFINITY, lrB = 0.f;

#pragma unroll 1
        for (int j = 0; j < nkt; ++j) {
            const us* kb = Kg + base  + (size_t)j * 64 * DH;
            const us* vb = Vt + baseV + j * 64;

            // K frags (A-operand) straight from L2: rows sub*16+l16, halves 0/1
            bf16x8 kf[4][2];
#pragma unroll
            for (int sub = 0; sub < 4; ++sub)
#pragma unroll
                for (int hh = 0; hh < 2; ++hh)
                    kf[sub][hh] = ld_frag(kb + (size_t)(sub * 16 + l16) * DH + hh * 32 + quad * 8);

            // S^T = K Q^T for both groups (K frags shared)
            f32x4 sA[4], sB[4];
#pragma unroll
            for (int sub = 0; sub < 4; ++sub) {
                f32x4 t = __builtin_amdgcn_mfma_f32_16x16x32_bf16(kf[sub][0], qfA0, zero4, 0, 0, 0);
                sA[sub]  = __builtin_amdgcn_mfma_f32_16x16x32_bf16(kf[sub][1], qfA1, t, 0, 0, 0);
                f32x4 u = __builtin_amdgcn_mfma_f32_16x16x32_bf16(kf[sub][0], qfB0, zero4, 0, 0, 0);
                sB[sub]  = __builtin_amdgcn_mfma_f32_16x16x32_bf16(kf[sub][1], qfB1, u, 0, 0, 0);
            }

            // V^T frags (A-operand) from L2: rows dsub*16+l16, key chunks kc*32+quad*8
            bf16x8 vf[4][2];
#pragma unroll
            for (int dsub = 0; dsub < 4; ++dsub)
#pragma unroll
                for (int kc = 0; kc < 2; ++kc)
                    vf[dsub][kc] = ld_frag(vb + (size_t)(dsub * 16 + l16) * TT + kc * 32 + quad * 8);

            // diagonal mask on last tile
            if (j == nkt - 1) {
#pragma unroll
                for (int sub = 0; sub < 4; ++sub)
#pragma unroll
                    for (int reg = 0; reg < 4; ++reg) {
                        int key = j * 64 + sub * 16 + quad * 4 + reg;
                        if (key > mA) sA[sub][reg] = -INFINITY;
                        if (key > mB) sB[sub][reg] = -INFINITY;
                    }
            }

            // online softmax, group A (per-lane 16 vals + 2 shuffles)
            {
                float mx = -INFINITY;
#pragma unroll
                for (int sub = 0; sub < 4; ++sub)
#pragma unroll
                    for (int reg = 0; reg < 4; ++reg) mx = fmaxf(mx, sA[sub][reg]);
                mx = fmaxf(mx, __shfl_xor(mx, 16));
                mx = fmaxf(mx, __shfl_xor(mx, 32));
                float mnew = fmaxf(mrA, mx);
                float alpha = exp2f(mrA - mnew);
                float rs = 0.f;
#pragma unroll
                for (int sub = 0; sub < 4; ++sub) {
                    float p0 = exp2f(sA[sub][0] - mnew), p1 = exp2f(sA[sub][1] - mnew);
                    float p2 = exp2f(sA[sub][2] - mnew), p3 = exp2f(sA[sub][3] - mnew);
                    rs += (p0 + p1) + (p2 + p3);
                    uint2 pk; pk.x = pack2bf(p0, p1); pk.y = pack2bf(p2, p3);
                    *reinterpret_cast<uint2*>(&myP[l16 * PST + sub * 16 + quad * 4]) = pk;
                }
                rs += __shfl_xor(rs, 16);
                rs += __shfl_xor(rs, 32);
                lrA = lrA * alpha + rs;
                mrA = mnew;
#pragma unroll
                for (int d = 0; d < 4; ++d) oA[d] *= alpha;
            }
            // group B
            {
                float mx = -INFINITY;
#pragma unroll
                for (int sub = 0; sub < 4; ++sub)
#pragma unroll
                    for (int reg = 0; reg < 4; ++reg) mx = fmaxf(mx, sB[sub][reg]);
                mx = fmaxf(mx, __shfl_xor(mx, 16));
                mx = fmaxf(mx, __shfl_xor(mx, 32));
                float mnew = fmaxf(mrB, mx);
                float alpha = exp2f(mrB - mnew);
                float rs = 0.f;
#pragma unroll
                for (int sub = 0; sub < 4; ++sub) {
                    float p0 = exp2f(sB[sub][0] - mnew), p1 = exp2f(sB[sub][1] - mnew);
                    float p2 = exp2f(sB[sub][2] - mnew), p3 = exp2f(sB[sub][3] - mnew);
                    rs += (p0 + p1) + (p2 + p3);
                    uint2 pk; pk.x = pack2bf(p0, p1); pk.y = pack2bf(p2, p3);
                    *reinterpret_cast<uint2*>(&myP[(16 + l16) * PST + sub * 16 + quad * 4]) = pk;
                }
                rs += __shfl_xor(rs, 16);
                rs += __shfl_xor(rs, 32);
                lrB = lrB * alpha + rs;
                mrB = mnew;
#pragma unroll
                for (int d = 0; d < 4; ++d) oB[d] *= alpha;
            }

            // O^T += V^T P (V frags shared A/B; same-wave LDS dep -> compiler waits)
#pragma unroll
            for (int kc = 0; kc < 2; ++kc) {
                bf16x8 pfA = *reinterpret_cast<const bf16x8*>(&myP[l16 * PST + kc * 32 + quad * 8]);
                bf16x8 pfB = *reinterpret_cast<const bf16x8*>(&myP[(16 + l16) * PST + kc * 32 + quad * 8]);
#pragma unroll
                for (int d = 0; d < 4; ++d) {
                    oA[d] = __builtin_amdgcn_mfma_f32_16x16x32_bf16(vf[d][kc], pfA, oA[d], 0, 0, 0);
                    oB[d] = __builtin_amdgcn_mfma_f32_16x16x32_bf16(vf[d][kc], pfB, oB[d], 0, 0, 0);
                }
            }
        }

        // epilogue: O^T[d][m] -> att[b, t=m, h*64+d], 8B packed stores
        const float invA = 1.f / lrA, invB = 1.f / lrB;
        us* orowA = Og + ((size_t)(b * TT + mA)) * CC + h * DH;
        us* orowB = Og + ((size_t)(b * TT + mB)) * CC + h * DH;
#pragma unroll
        for (int d = 0; d < 4; ++d) {
            uint2 pa, pb;
            pa.x = pack2bf(oA[d][0] * invA, oA[d][1] * invA);
            pa.y = pack2bf(oA[d][2] * invA, oA[d][3] * invA);
            pb.x = pack2bf(oB[d][0] * invB, oB[d][1] * invB);
            pb.y = pack2bf(oB[d][2] * invB, oB[d][3] * invB);
            *reinterpret_cast<uint2*>(orowA + d * 16 + quad * 4) = pa;
            *reinterpret_cast<uint2*>(orowB + d * 16 + quad * 4) = pb;
        }
    }
}

// ---------- launch ----------
extern "C" void kernel_launch(void* const* d_in, const int* in_sizes, int n_in,
                              void* d_out, int out_size, void* d_ws, size_t ws_size,
                              hipStream_t stream)
{
    const float* x      = (const float*)d_in[0];
    const float* w_attn = (const float*)d_in[1];
    const float* b_attn = (const float*)d_in[2];
    const float* w_proj = (const float*)d_in[3];
    const float* b_proj = (const float*)d_in[4];
    float* out = (float*)d_out;

    char* ws = (char*)d_ws;
    size_t off = 0;
    auto alloc = [&](size_t bytes) {
        void* p = ws + off;
        off += (bytes + 255) & ~(size_t)255;
        return p;
    };
    us* wtA = (us*)alloc((size_t)(3 * CC) * CC * 2);  // [2304][768] bf16
    us* wtP = (us*)alloc((size_t)CC * CC * 2);        // [768][768]  bf16
    us* xb  = (us*)alloc((size_t)MM * CC * 2);        // x as bf16
    us* Qb  = (us*)alloc((size_t)MM * CC * 2);        // [B,H,T,D]
    us* Kb  = (us*)alloc((size_t)MM * CC * 2);        // [B,H,T,D]
    us* Vtb = (us*)alloc((size_t)MM * CC * 2);        // V^T [B,H,D,T]
    us* att = (us*)alloc((size_t)MM * CC * 2);        // [B,T,C]

    cast_k<<<1024, 256, 0, stream>>>(x, xb, MM * CC / 4);
    transpose_k<<<dim3((3 * CC) / 32, CC / 32), dim3(32, 8), 0, stream>>>(w_attn, wtA, CC, 3 * CC);
    transpose_k<<<dim3(CC / 32, CC / 32), dim3(32, 8), 0, stream>>>(w_proj, wtP, CC, CC);

    gemm_bt<1><<<dim3((3 * CC) / BN, MM / BM), 256, 0, stream>>>(
        xb, wtA, b_attn, nullptr, Qb, Kb, Vtb, MM, 3 * CC, CC);

    attn_k<<<dim3(16 * BB * NH), 128, 0, stream>>>(Qb, Kb, Vtb, att);

    gemm_bt<0><<<dim3(CC / BN, MM / BM), 256, 0, stream>>>(
        att, wtP, b_proj, out, nullptr, nullptr, nullptr, MM, CC, CC);

    (void)in_sizes; (void)n_in; (void)out_size; (void)ws_size;
}